// Round 13
// baseline (616.406 us; speedup 1.0000x reference)
//
#include <hip/hip_runtime.h>
#include <hip/hip_bf16.h>

#define N_SRCN 200000
#define N_DSTN 50000
#define NEDGE 800000
#define KIN 256
#define NF 192        // H*OUT = 3*64
#define SLOPE 0.2f
#define TILES16 12500 // 16-row tiles
#define NWAVES 4096   // 256 blocks x 16 waves

typedef __attribute__((ext_vector_type(8))) short bf16x8;
typedef __attribute__((ext_vector_type(4))) float f32x4;

__device__ __forceinline__ unsigned short f2bf(float f) {
    union { float f; unsigned int u; } v; v.f = f;
    unsigned int u = v.u;
    return (unsigned short)((u + 0x7FFFu + ((u >> 16) & 1u)) >> 16);  // RNE
}
__device__ __forceinline__ float bf2f(unsigned short h) {
    union { unsigned int u; float f; } v; v.u = ((unsigned int)h) << 16;
    return v.f;
}
__device__ __forceinline__ unsigned int cvt2(float lo, float hi) {
    __hip_bfloat162 h = __float22bfloat162_rn(float2{lo, hi});
    union { __hip_bfloat162 h; unsigned int u; } c; c.h = h;
    return c.u;
}
__device__ __forceinline__ void gl_lds16(const void* g, void* l) {
    __builtin_amdgcn_global_load_lds(
        (const __attribute__((address_space(1))) unsigned int*)g,
        (__attribute__((address_space(3))) unsigned int*)l, 16, 0, 0);
}

// ---------------- merged prep: blocks 0-23 pack W; blocks 24+ build row_ptr --
__global__ void prep_kernel(const float* __restrict__ W, unsigned short* __restrict__ Wp,
                            const int* __restrict__ dst, int* __restrict__ rp) {
    const int bid = blockIdx.x;
    if (bid < 24) {
        int tid = bid * 256 + threadIdx.x;
        if (tid >= 12 * 8 * 64) return;
        int lane = tid & 63;
        int g = tid >> 6;
        int nt = g % 12, ks = g / 12;
        int col = nt * 16 + (lane & 15);
        int k = ks * 32 + (lane >> 4) * 8;
        const float* wsrc = &W[col * KIN + k];
        unsigned short* o = &Wp[tid * 8];
        #pragma unroll
        for (int j = 0; j < 8; ++j) o[j] = f2bf(wsrc[j]);
    } else {
        int d = (bid - 24) * 256 + threadIdx.x;
        if (d > N_DSTN) return;
        int lo = 0, hi = NEDGE;
        while (lo < hi) {
            int mid = (lo + hi) >> 1;
            if (dst[mid] < d) lo = mid + 1; else hi = mid;
        }
        rp[d] = lo;
    }
}

// ---------------- PROBE 1: A-load path only ----------------------------------
// Exact R11 tile/wave mapping and load addresses; consumes every loaded float
// into a sum written to el4's unused .w lane (read by gather, never used).
__global__ void __launch_bounds__(1024, 1)
probe_load(const float* __restrict__ x, float* __restrict__ el4) {
    const int t = threadIdx.x;
    const int wid = t >> 6, lane = t & 63;
    const int al = lane & 15, ah = lane >> 4;
    const int gw = blockIdx.x * 16 + wid;
    float s = 0.f;
    for (int tile = gw; tile < TILES16; tile += NWAVES) {
        const float* xrow = &x[(size_t)(tile * 16 + al) * KIN + ah * 8];
        #pragma unroll
        for (int k = 0; k < 8; ++k) {
            const float4 a0 = *(const float4*)&xrow[k * 32];
            const float4 a1 = *(const float4*)&xrow[k * 32 + 4];
            s += a0.x + a0.y + a0.z + a0.w + a1.x + a1.y + a1.z + a1.w;
        }
    }
    if (lane == 0) el4[(size_t)gw * 4 + 3] = s;   // .w lane: loaded, never used
}

// ---------------- PROBE 2: full pipeline MINUS feat stores -------------------
// acc is fully consumed by the el/er reduction -> nothing dead. Writes the
// (identical) el/er values; real gemm rewrites them afterwards.
__global__ void __launch_bounds__(1024, 1)
probe_nostore(const float* __restrict__ x, const unsigned short* __restrict__ Wp,
              const float* __restrict__ attn_l, const float* __restrict__ attn_r,
              float* __restrict__ el4, float* __restrict__ er4) {
    __shared__ unsigned short Bl[12 * 8 * 512];
    const int t = threadIdx.x;
    const int wid = t >> 6, lane = t & 63;
    const int al = lane & 15, ah = lane >> 4;

    #pragma unroll
    for (int i = 0; i < 6; ++i) {
        const int off = (i * 16 + wid) * 1024;
        gl_lds16((const char*)Wp + off + lane * 16, (char*)Bl + off);
    }
    asm volatile("s_waitcnt vmcnt(0)" ::: "memory");
    __syncthreads();

    float Al[12], Ar[12];
    #pragma unroll
    for (int nt = 0; nt < 12; ++nt) {
        Al[nt] = attn_l[nt * 16 + al];
        Ar[nt] = attn_r[nt * 16 + al];
    }

    const int gw = blockIdx.x * 16 + wid;
    for (int tile = gw; tile < TILES16; tile += NWAVES) {
        const int r0 = tile * 16;
        const float* xrow = &x[(size_t)(r0 + al) * KIN + ah * 8];

        f32x4 acc[12] = {};
        #pragma unroll
        for (int ks = 0; ks < 8; ++ks) {
            const float4 a0 = *(const float4*)&xrow[ks * 32];
            const float4 a1 = *(const float4*)&xrow[ks * 32 + 4];
            union { bf16x8 v; unsigned int u[4]; } av;
            av.u[0] = cvt2(a0.x, a0.y);
            av.u[1] = cvt2(a0.z, a0.w);
            av.u[2] = cvt2(a1.x, a1.y);
            av.u[3] = cvt2(a1.z, a1.w);
            #pragma unroll
            for (int nt = 0; nt < 12; ++nt) {
                const bf16x8 bv = *(const bf16x8*)&Bl[(ks * 12 + nt) * 512 + lane * 8];
                acc[nt] = __builtin_amdgcn_mfma_f32_16x16x32_bf16(av.v, bv, acc[nt], 0, 0, 0);
            }
        }
        // NO feat stores. el/er epilogue consumes all of acc.
        #pragma unroll
        for (int h = 0; h < 3; ++h) {
            #pragma unroll
            for (int e = 0; e < 4; ++e) {
                float sl = 0.f, sr = 0.f;
                #pragma unroll
                for (int q = 0; q < 4; ++q) {
                    const int nt = h * 4 + q;
                    sl += acc[nt][e] * Al[nt];
                    sr += acc[nt][e] * Ar[nt];
                }
                #pragma unroll
                for (int m = 1; m <= 8; m <<= 1) {
                    sl += __shfl_xor(sl, m);
                    sr += __shfl_xor(sr, m);
                }
                if (al == 0) {
                    const int row = r0 + ah * 4 + e;
                    el4[(size_t)row * 4 + h] = sl;
                    if (row < N_DSTN) er4[(size_t)row * 4 + h] = sr;
                }
            }
        }
    }
}

// ---------------- GEMM (real, R11 verbatim) ----------------------------------
__global__ void __launch_bounds__(1024, 1)
gemm_feat(const float* __restrict__ x, const unsigned short* __restrict__ Wp,
          const float* __restrict__ attn_l, const float* __restrict__ attn_r,
          unsigned short* __restrict__ feat,
          float* __restrict__ el4, float* __restrict__ er4) {
    __shared__ unsigned short Bl[12 * 8 * 512];
    const int t = threadIdx.x;
    const int wid = t >> 6, lane = t & 63;
    const int al = lane & 15, ah = lane >> 4;

    #pragma unroll
    for (int i = 0; i < 6; ++i) {
        const int off = (i * 16 + wid) * 1024;
        gl_lds16((const char*)Wp + off + lane * 16, (char*)Bl + off);
    }
    asm volatile("s_waitcnt vmcnt(0)" ::: "memory");
    __syncthreads();

    float Al[12], Ar[12];
    #pragma unroll
    for (int nt = 0; nt < 12; ++nt) {
        Al[nt] = attn_l[nt * 16 + al];
        Ar[nt] = attn_r[nt * 16 + al];
    }

    const int gw = blockIdx.x * 16 + wid;
    for (int tile = gw; tile < TILES16; tile += NWAVES) {
        const int r0 = tile * 16;
        const float* xrow = &x[(size_t)(r0 + al) * KIN + ah * 8];

        f32x4 acc[12] = {};
        #pragma unroll
        for (int ks = 0; ks < 8; ++ks) {
            const float4 a0 = *(const float4*)&xrow[ks * 32];
            const float4 a1 = *(const float4*)&xrow[ks * 32 + 4];
            union { bf16x8 v; unsigned int u[4]; } av;
            av.u[0] = cvt2(a0.x, a0.y);
            av.u[1] = cvt2(a0.z, a0.w);
            av.u[2] = cvt2(a1.x, a1.y);
            av.u[3] = cvt2(a1.z, a1.w);
            #pragma unroll
            for (int nt = 0; nt < 12; ++nt) {
                const bf16x8 bv = *(const bf16x8*)&Bl[(ks * 12 + nt) * 512 + lane * 8];
                acc[nt] = __builtin_amdgcn_mfma_f32_16x16x32_bf16(av.v, bv, acc[nt], 0, 0, 0);
            }
        }

        #pragma unroll
        for (int nt = 0; nt < 12; ++nt) {
            const int col = nt * 16 + al;
            #pragma unroll
            for (int e = 0; e < 4; ++e) {
                const int row = r0 + ah * 4 + e;
                feat[(size_t)row * NF + col] = f2bf(acc[nt][e]);
            }
        }

        #pragma unroll
        for (int h = 0; h < 3; ++h) {
            #pragma unroll
            for (int e = 0; e < 4; ++e) {
                float sl = 0.f, sr = 0.f;
                #pragma unroll
                for (int q = 0; q < 4; ++q) {
                    const int nt = h * 4 + q;
                    sl += acc[nt][e] * Al[nt];
                    sr += acc[nt][e] * Ar[nt];
                }
                #pragma unroll
                for (int m = 1; m <= 8; m <<= 1) {
                    sl += __shfl_xor(sl, m);
                    sr += __shfl_xor(sr, m);
                }
                if (al == 0) {
                    const int row = r0 + ah * 4 + e;
                    el4[(size_t)row * 4 + h] = sl;
                    if (row < N_DSTN) er4[(size_t)row * 4 + h] = sr;
                }
            }
        }
    }
}

// ---------------- gather: edge softmax (no max shift) + weighted accumulate --
__launch_bounds__(256)
__global__ void gather_kernel(const unsigned short* __restrict__ feat,
                              const float* __restrict__ el4, const float* __restrict__ er4,
                              const int* __restrict__ src, const int* __restrict__ rp,
                              float* __restrict__ out) {
    const int lane = threadIdx.x & 63;
    const int d = (blockIdx.x * blockDim.x + threadIdx.x) >> 6;
    if (d >= N_DSTN) return;
    const int lo = rp[d], hi = rp[d + 1];
    const float4 erv = *(const float4*)&er4[(size_t)d * 4];

    float a0 = 0.f, a1 = 0.f, a2 = 0.f, s0 = 0.f, s1 = 0.f, s2 = 0.f;
    for (int base = lo; base < hi; base += 64) {
        const int cnt = min(64, hi - base);
        int sv = 0; float w0 = 0.f, w1 = 0.f, w2 = 0.f;
        if (lane < cnt) {
            sv = src[base + lane];
            const float4 elv = *(const float4*)&el4[(size_t)sv * 4];
            float e0 = elv.x + erv.x; e0 = e0 >= 0.f ? e0 : SLOPE * e0; w0 = __expf(e0);
            float e1 = elv.y + erv.y; e1 = e1 >= 0.f ? e1 : SLOPE * e1; w1 = __expf(e1);
            float e2 = elv.z + erv.z; e2 = e2 >= 0.f ? e2 : SLOPE * e2; w2 = __expf(e2);
        }
        int j = 0;
        for (; j + 8 <= cnt; j += 8) {
            unsigned short f0[8], f1[8], f2[8];
            float u0[8], u1[8], u2[8];
            #pragma unroll
            for (int q = 0; q < 8; ++q) {
                const int sj = __shfl(sv, j + q);
                const unsigned short* fp = &feat[(size_t)sj * NF + lane];
                f0[q] = fp[0]; f1[q] = fp[64]; f2[q] = fp[128];
                u0[q] = __shfl(w0, j + q);
                u1[q] = __shfl(w1, j + q);
                u2[q] = __shfl(w2, j + q);
            }
            #pragma unroll
            for (int q = 0; q < 8; ++q) {
                s0 += u0[q]; a0 += u0[q] * bf2f(f0[q]);
                s1 += u1[q]; a1 += u1[q] * bf2f(f1[q]);
                s2 += u2[q]; a2 += u2[q] * bf2f(f2[q]);
            }
        }
        for (; j < cnt; ++j) {
            const int sj = __shfl(sv, j);
            const float u0 = __shfl(w0, j);
            const float u1 = __shfl(w1, j);
            const float u2 = __shfl(w2, j);
            const unsigned short* fp = &feat[(size_t)sj * NF + lane];
            s0 += u0; a0 += u0 * bf2f(fp[0]);
            s1 += u1; a1 += u1 * bf2f(fp[64]);
            s2 += u2; a2 += u2 * bf2f(fp[128]);
        }
    }
    if (hi == lo) { s0 = 1.f; s1 = 1.f; s2 = 1.f; }
    float* op = &out[(size_t)d * NF];
    op[lane]       = a0 / s0;
    op[64 + lane]  = a1 / s1;
    op[128 + lane] = a2 / s2;
}

extern "C" void kernel_launch(void* const* d_in, const int* in_sizes, int n_in,
                              void* d_out, int out_size, void* d_ws, size_t ws_size,
                              hipStream_t stream) {
    const float* x      = (const float*)d_in[0];
    const float* W      = (const float*)d_in[1];
    const float* attn_l = (const float*)d_in[2];
    const float* attn_r = (const float*)d_in[3];
    const int*   src    = (const int*)d_in[4];
    const int*   dst    = (const int*)d_in[5];
    float* out = (float*)d_out;

    char* ws = (char*)d_ws;
    unsigned short* feat = (unsigned short*)ws;             // 76,800,000 B
    float* el4 = (float*)(ws + 76800000);                   // 3,200,000 B
    float* er4 = (float*)(ws + 80000000);                   //   800,000 B
    unsigned short* Wp = (unsigned short*)(ws + 80800000);  //    98,304 B
    int*   rp = (int*)(ws + 80898304);                      //   200,004 B

    prep_kernel<<<24 + 196, 256, 0, stream>>>(W, Wp, dst, rp);
    probe_load<<<256, 1024, 0, stream>>>(x, el4);
    probe_nostore<<<256, 1024, 0, stream>>>(x, Wp, attn_l, attn_r, el4, er4);
    gemm_feat<<<256, 1024, 0, stream>>>(x, Wp, attn_l, attn_r, feat, el4, er4);
    gather_kernel<<<12500, 256, 0, stream>>>(feat, el4, er4, src, rp, out);
}

// Round 16
// 191.743 us; speedup vs baseline: 3.2148x; 3.2148x over previous
//
#include <hip/hip_runtime.h>
#include <hip/hip_bf16.h>

#define N_SRCN 200000
#define N_DSTN 50000
#define NEDGE 800000
#define KIN 256
#define NF 192        // H*OUT = 3*64
#define SLOPE 0.2f
#define TILES16 12500 // 16-row tiles
#define NGRP 1563     // ceil(12500/8); grid = 3*NGRP blocks

typedef __attribute__((ext_vector_type(8))) short bf16x8;
typedef __attribute__((ext_vector_type(4))) float f32x4;

__device__ __forceinline__ unsigned short f2bf(float f) {
    union { float f; unsigned int u; } v; v.f = f;
    unsigned int u = v.u;
    return (unsigned short)((u + 0x7FFFu + ((u >> 16) & 1u)) >> 16);  // RNE
}
__device__ __forceinline__ float bf2f(unsigned short h) {
    union { unsigned int u; float f; } v; v.u = ((unsigned int)h) << 16;
    return v.f;
}
__device__ __forceinline__ unsigned int cvt2(float lo, float hi) {
    __hip_bfloat162 h = __float22bfloat162_rn(float2{lo, hi});
    union { __hip_bfloat162 h; unsigned int u; } c; c.h = h;
    return c.u;
}
__device__ __forceinline__ void gl_lds16(const void* g, void* l) {
    __builtin_amdgcn_global_load_lds(
        (const __attribute__((address_space(1))) unsigned int*)g,
        (__attribute__((address_space(3))) unsigned int*)l, 16, 0, 0);
}

// ---------------- prep: pack W head-major (3 x 32 frags) + row_ptr -----------
// fragment f = h*32 + ks*4 + q  (nt = h*4+q):
// Wp3[f*512 + lane*8 + j] = bf16(W[(nt*16+(lane&15))*KIN + ks*32+(lane>>4)*8+j])
__global__ void prep_kernel(const float* __restrict__ W, unsigned short* __restrict__ Wp3,
                            const int* __restrict__ dst, int* __restrict__ rp) {
    const int bid = blockIdx.x;
    if (bid < 24) {
        int tid = bid * 256 + threadIdx.x;
        if (tid >= 96 * 64) return;
        int lane = tid & 63;
        int g = tid >> 6;                 // fragment id 0..95
        int h = g / 32, rem = g % 32;
        int ks = rem / 4, q = rem % 4;
        int nt = h * 4 + q;
        int col = nt * 16 + (lane & 15);
        int k = ks * 32 + (lane >> 4) * 8;
        const float* wsrc = &W[col * KIN + k];
        unsigned short* o = &Wp3[(size_t)g * 512 + lane * 8];
        #pragma unroll
        for (int j = 0; j < 8; ++j) o[j] = f2bf(wsrc[j]);
    } else {
        int d = (bid - 24) * 256 + threadIdx.x;
        if (d > N_DSTN) return;
        int lo = 0, hi = NEDGE;
        while (lo < hi) {
            int mid = (lo + hi) >> 1;
            if (dst[mid] < d) lo = mid + 1; else hi = mid;
        }
        rp[d] = lo;
    }
}

// ---------------- GEMM: feat = x @ W^T (bf16 MFMA) + fused el/er -------------
// Grid 4689 = 1563 tile-groups x 3 head-types (htype = bid%3: adjacent bids
// share x rows -> L3 locality). Type owns head htype's 4 col-tiles (64 cols =
// EXACTLY one 128B L2 line per feat row -> line-exclusive writers; no cross-
// XCD false sharing — R14/R15 bug). Block: stage 32KB of Wp3, 1 barrier, then
// 8 independent waves each compute one 16-row tile. el_h/er_h: 4B/row scalar
// buffers; block covers 128 rows = 4 aligned lines -> single writer per line.
__global__ void __launch_bounds__(512, 4)
gemm_feat(const float* __restrict__ x, const unsigned short* __restrict__ Wp3,
          const float* __restrict__ attn_l, const float* __restrict__ attn_r,
          unsigned short* __restrict__ feat,
          float* __restrict__ el0, float* __restrict__ el1, float* __restrict__ el2,
          float* __restrict__ er0, float* __restrict__ er1, float* __restrict__ er2) {
    __shared__ unsigned short Bl[32 * 512];       // 32 KB
    const int t = threadIdx.x;
    const int wid = t >> 6, lane = t & 63;
    const int al = lane & 15, ah = lane >> 4;
    const int grp = blockIdx.x / 3;
    const int htype = blockIdx.x % 3;

    // ---- stage this head's 32 KB (4 sweeps x 8KB) ----
    const char* wsrc = (const char*)Wp3 + (size_t)htype * 32768;
    #pragma unroll
    for (int i = 0; i < 4; ++i) {
        const int off = (i * 8 + wid) * 1024;     // wave-uniform byte offset
        gl_lds16(wsrc + off + lane * 16, (char*)Bl + off);
    }
    asm volatile("s_waitcnt vmcnt(0)" ::: "memory");
    __syncthreads();
    // ---- no barriers after this point ----

    float Al[4], Ar[4];
    #pragma unroll
    for (int q = 0; q < 4; ++q) {
        Al[q] = attn_l[(htype * 4 + q) * 16 + al];
        Ar[q] = attn_r[(htype * 4 + q) * 16 + al];
    }

    const int tile = grp * 8 + wid;
    if (tile >= TILES16) return;
    const int r0 = tile * 16;
    const float* xrow = &x[(size_t)(r0 + al) * KIN + ah * 8];

    f32x4 acc[4] = {};
    #pragma unroll
    for (int ks = 0; ks < 8; ++ks) {
        const float4 a0 = *(const float4*)&xrow[ks * 32];
        const float4 a1 = *(const float4*)&xrow[ks * 32 + 4];
        union { bf16x8 v; unsigned int u[4]; } av;
        av.u[0] = cvt2(a0.x, a0.y);
        av.u[1] = cvt2(a0.z, a0.w);
        av.u[2] = cvt2(a1.x, a1.y);
        av.u[3] = cvt2(a1.z, a1.w);
        #pragma unroll
        for (int q = 0; q < 4; ++q) {
            const bf16x8 bv = *(const bf16x8*)&Bl[(ks * 4 + q) * 512 + lane * 8];
            acc[q] = __builtin_amdgcn_mfma_f32_16x16x32_bf16(av.v, bv, acc[q], 0, 0, 0);
        }
    }

    // ---- feat store (C/D: col=(htype*4+q)*16+al, row=ah*4+e [m89]) ----
    #pragma unroll
    for (int q = 0; q < 4; ++q) {
        const int col = (htype * 4 + q) * 16 + al;
        #pragma unroll
        for (int e = 0; e < 4; ++e) {
            const int row = r0 + ah * 4 + e;
            feat[(size_t)row * NF + col] = f2bf(acc[q][e]);
        }
    }

    // ---- el/er for this head (16-lane al-reduce) ----
    float* elh = htype == 0 ? el0 : (htype == 1 ? el1 : el2);
    float* erh = htype == 0 ? er0 : (htype == 1 ? er1 : er2);
    #pragma unroll
    for (int e = 0; e < 4; ++e) {
        float sl = 0.f, sr = 0.f;
        #pragma unroll
        for (int q = 0; q < 4; ++q) {
            sl += acc[q][e] * Al[q];
            sr += acc[q][e] * Ar[q];
        }
        #pragma unroll
        for (int m = 1; m <= 8; m <<= 1) {
            sl += __shfl_xor(sl, m);
            sr += __shfl_xor(sr, m);
        }
        if (al == 0) {
            const int row = r0 + ah * 4 + e;
            elh[row] = sl;
            if (row < N_DSTN) erh[row] = sr;
        }
    }
}

// ---------------- gather: edge softmax (no max shift) + weighted accumulate --
__launch_bounds__(256)
__global__ void gather_kernel(const unsigned short* __restrict__ feat,
                              const float* __restrict__ el0, const float* __restrict__ el1,
                              const float* __restrict__ el2,
                              const float* __restrict__ er0, const float* __restrict__ er1,
                              const float* __restrict__ er2,
                              const int* __restrict__ src, const int* __restrict__ rp,
                              float* __restrict__ out) {
    const int lane = threadIdx.x & 63;
    const int d = (blockIdx.x * blockDim.x + threadIdx.x) >> 6;
    if (d >= N_DSTN) return;
    const int lo = rp[d], hi = rp[d + 1];
    const float erv0 = er0[d], erv1 = er1[d], erv2 = er2[d];

    float a0 = 0.f, a1 = 0.f, a2 = 0.f, s0 = 0.f, s1 = 0.f, s2 = 0.f;
    for (int base = lo; base < hi; base += 64) {
        const int cnt = min(64, hi - base);
        int sv = 0; float w0 = 0.f, w1 = 0.f, w2 = 0.f;
        if (lane < cnt) {
            sv = src[base + lane];
            float e0 = el0[sv] + erv0; e0 = e0 >= 0.f ? e0 : SLOPE * e0; w0 = __expf(e0);
            float e1 = el1[sv] + erv1; e1 = e1 >= 0.f ? e1 : SLOPE * e1; w1 = __expf(e1);
            float e2 = el2[sv] + erv2; e2 = e2 >= 0.f ? e2 : SLOPE * e2; w2 = __expf(e2);
        }
        int j = 0;
        for (; j + 8 <= cnt; j += 8) {
            unsigned short f0[8], f1[8], f2[8];
            float u0[8], u1[8], u2[8];
            #pragma unroll
            for (int q = 0; q < 8; ++q) {
                const int sj = __shfl(sv, j + q);
                const unsigned short* fp = &feat[(size_t)sj * NF + lane];
                f0[q] = fp[0]; f1[q] = fp[64]; f2[q] = fp[128];
                u0[q] = __shfl(w0, j + q);
                u1[q] = __shfl(w1, j + q);
                u2[q] = __shfl(w2, j + q);
            }
            #pragma unroll
            for (int q = 0; q < 8; ++q) {
                s0 += u0[q]; a0 += u0[q] * bf2f(f0[q]);
                s1 += u1[q]; a1 += u1[q] * bf2f(f1[q]);
                s2 += u2[q]; a2 += u2[q] * bf2f(f2[q]);
            }
        }
        for (; j < cnt; ++j) {
            const int sj = __shfl(sv, j);
            const float u0 = __shfl(w0, j);
            const float u1 = __shfl(w1, j);
            const float u2 = __shfl(w2, j);
            const unsigned short* fp = &feat[(size_t)sj * NF + lane];
            s0 += u0; a0 += u0 * bf2f(fp[0]);
            s1 += u1; a1 += u1 * bf2f(fp[64]);
            s2 += u2; a2 += u2 * bf2f(fp[128]);
        }
    }
    if (hi == lo) { s0 = 1.f; s1 = 1.f; s2 = 1.f; }
    float* op = &out[(size_t)d * NF];
    op[lane]       = a0 / s0;
    op[64 + lane]  = a1 / s1;
    op[128 + lane] = a2 / s2;
}

extern "C" void kernel_launch(void* const* d_in, const int* in_sizes, int n_in,
                              void* d_out, int out_size, void* d_ws, size_t ws_size,
                              hipStream_t stream) {
    const float* x      = (const float*)d_in[0];
    const float* W      = (const float*)d_in[1];
    const float* attn_l = (const float*)d_in[2];
    const float* attn_r = (const float*)d_in[3];
    const int*   src    = (const int*)d_in[4];
    const int*   dst    = (const int*)d_in[5];
    float* out = (float*)d_out;

    char* ws = (char*)d_ws;
    unsigned short* feat = (unsigned short*)ws;             // 76,800,000 B
    float* el0 = (float*)(ws + 76800000);                   // 800,000 B each
    float* el1 = (float*)(ws + 77600000);
    float* el2 = (float*)(ws + 78400000);
    float* er0 = (float*)(ws + 79200000);                   // 200,000 B each
    float* er1 = (float*)(ws + 79400000);
    float* er2 = (float*)(ws + 79600000);
    unsigned short* Wp3 = (unsigned short*)(ws + 79800000); //  98,304 B
    int*   rp = (int*)(ws + 79898304);                      // 200,004 B

    prep_kernel<<<24 + 196, 256, 0, stream>>>(W, Wp3, dst, rp);
    gemm_feat<<<3 * NGRP, 512, 0, stream>>>(x, Wp3, attn_l, attn_r, feat,
                                            el0, el1, el2, er0, er1, er2);
    gather_kernel<<<12500, 256, 0, stream>>>(feat, el0, el1, el2, er0, er1, er2,
                                             src, rp, out);
}